// Round 18
// baseline (341.315 us; speedup 1.0000x reference)
//
#include <hip/hip_runtime.h>
#include <hip/hip_bf16.h>

// GatingNetwork: B=16384 rows, D=4096, H=OUT=7.
// R18: R16 (best, 147us) with minimal barrier scope: ONE row per block.
// Lesson R11/R16/R17: smaller barrier scope beats higher occupancy (R16's
// 8-wave barrier @41% occ beat R11's 16-wave @81% and R17's 16-wave @44%).
// Here: 256 thr = 4 waves = the 4 quarters of one row -> the barrier spans
// only the waves that exchange partials. Grid 16384 sequential blocks; up to
// 8 independent row-blocks/CU whose barriers are mutually uncorrelated ->
// some blocks always bursting while others reduce. Per-wave code identical
// to R16: weights in 14 uint4 registers (no ds_read chain), 8-load burst,
// 49-op packed reduce, tiny-LDS exchange, lane-uniform alpha, register
// combine. launch_bounds(256,8): VGPR cap 64 (R16 measured exactly 64).

constexpr int Dk  = 4096;
constexpr int Hk  = 7;
constexpr int NPAIR = Dk / 512;                  // 8 pair-iters (512 floats)
constexpr int NWE   = Hk * NPAIR * 64;           // 3584 uint4 weight entries
constexpr int WPK_WORDS = NWE * 4;               // 14336 u32 words (57344 B)
constexpr size_t WS_NEEDED = (size_t)WPK_WORDS * 4 + 64;

constexpr int NTH = 256;                         // 4 waves = 1 row
constexpr int RPB = 1;

// gc floats at word offset WPK_WORDS: b1[7], s_j[7], sum(b2) at [14].
__global__ void gating_prep(const float* __restrict__ W1,
                            const float* __restrict__ b1,
                            const float* __restrict__ W2,
                            const float* __restrict__ b2,
                            unsigned int* __restrict__ wsw)
{
    const int t = blockIdx.x * blockDim.x + threadIdx.x;   // one thread/uint4
    if (t < NWE) {
        const int j    = t / (NPAIR * 64);
        const int kk   = (t / 64) % NPAIR;
        const int lane = t & 63;
        const int vi0  = (2 * kk) * 64 + lane;             // float4 idx, iter A
        unsigned int w[4];
        #pragma unroll
        for (int h = 0; h < 2; ++h) {                      // iter A / iter B
            const int vi = vi0 + h * 64;
            #pragma unroll
            for (int p = 0; p < 2; ++p) {                  // element pair
                const int d0 = 4 * vi + 2 * p;
                const unsigned int lo = (unsigned int)__bfloat16_as_ushort(
                    __float2bfloat16(W1[(long long)d0 * Hk + j]));
                const unsigned int hi = (unsigned int)__bfloat16_as_ushort(
                    __float2bfloat16(W1[(long long)(d0 + 1) * Hk + j]));
                w[h * 2 + p] = lo | (hi << 16);
            }
        }
        reinterpret_cast<uint4*>(wsw)[t] = make_uint4(w[0], w[1], w[2], w[3]);
    }
    if (blockIdx.x == 0 && threadIdx.x == 0) {
        float* c = reinterpret_cast<float*>(wsw) + WPK_WORDS;
        #pragma unroll
        for (int j = 0; j < Hk; ++j) {
            c[j] = b1[j];
            float s = 0.f;
            #pragma unroll
            for (int k = 0; k < Hk; ++k) s += W2[j * Hk + k];
            c[Hk + j] = s;
        }
        float sb2 = 0.f;
        #pragma unroll
        for (int k = 0; k < Hk; ++k) sb2 += b2[k];
        c[14] = sb2;
    }
}

__device__ __forceinline__ float bf_lo(unsigned int u) {
    return __uint_as_float(u << 16);
}
__device__ __forceinline__ float bf_hi(unsigned int u) {
    return __uint_as_float(u & 0xFFFF0000u);
}

__global__ __launch_bounds__(NTH, 8)
void gating_wave(const float* __restrict__ f1,
                 const float* __restrict__ f2,
                 const uint4* __restrict__ wpk,   // [7][8][64] packed weights
                 const float* __restrict__ gc,    // b1[7], s[7], sb2
                 float* __restrict__ out,
                 int rows)
{
    __shared__ float red[2][Hk][4];              // 224 B

    const int q    = threadIdx.x >> 6;           // quarter of the row (wave id)
    const int lane = threadIdx.x & 63;
    const int vq0  = 4 * q * 64 + lane;          // float4 idx within row

    // ---- One-time: this wave's weight fragment -> 14 uint4 registers ----
    uint4 wr0[Hk], wr1[Hk];                      // kk = 2q, 2q+1
    #pragma unroll
    for (int j = 0; j < Hk; ++j) {
        wr0[j] = wpk[(j * NPAIR + 2 * q)     * 64 + lane];
        wr1[j] = wpk[(j * NPAIR + 2 * q + 1) * 64 + lane];
    }
    // Hoist gate constants.
    float b1r[Hk], sr[Hk];
    #pragma unroll
    for (int j = 0; j < Hk; ++j) { b1r[j] = gc[j]; sr[j] = gc[Hk + j]; }

    int row = blockIdx.x;
    if (row >= rows) row = rows - 1;
    const long long base = (long long)row * Dk;
    const float4* __restrict__ f1v = reinterpret_cast<const float4*>(f1 + base);
    const float4* __restrict__ f2v = reinterpret_cast<const float4*>(f2 + base);

    // ---- Burst this quarter's 8 loads (8 KB in flight) ----
    float4 a[4], b[4];
    #pragma unroll
    for (int i = 0; i < 4; ++i) {
        a[i] = f1v[vq0 + i * 64];
        b[i] = f2v[vq0 + i * 64];
    }
    __builtin_amdgcn_sched_barrier(0);           // keep the 8 loads batched

    float acc1[Hk], acc2[Hk];
    #pragma unroll
    for (int j = 0; j < Hk; ++j) { acc1[j] = 0.f; acc2[j] = 0.f; }

    // ---- Gate FMAs: pure VALU, weights from registers ----
    #pragma unroll
    for (int kk2 = 0; kk2 < 2; ++kk2) {
        const float4 xa0 = a[2 * kk2],     xb0 = b[2 * kk2];
        const float4 xa1 = a[2 * kk2 + 1], xb1 = b[2 * kk2 + 1];
        #pragma unroll
        for (int j = 0; j < Hk; ++j) {
            const uint4 u = kk2 ? wr1[j] : wr0[j];
            const float w0 = bf_lo(u.x), w1 = bf_hi(u.x);
            const float w2 = bf_lo(u.y), w3 = bf_hi(u.y);
            const float w4 = bf_lo(u.z), w5 = bf_hi(u.z);
            const float w6 = bf_lo(u.w), w7 = bf_hi(u.w);
            acc1[j] = fmaf(xa0.x, w0, fmaf(xa0.y, w1,
                      fmaf(xa0.z, w2, fmaf(xa0.w, w3, acc1[j]))));
            acc1[j] = fmaf(xa1.x, w4, fmaf(xa1.y, w5,
                      fmaf(xa1.z, w6, fmaf(xa1.w, w7, acc1[j]))));
            acc2[j] = fmaf(xb0.x, w0, fmaf(xb0.y, w1,
                      fmaf(xb0.z, w2, fmaf(xb0.w, w3, acc2[j]))));
            acc2[j] = fmaf(xb1.x, w4, fmaf(xb1.y, w5,
                      fmaf(xb1.z, w6, fmaf(xb1.w, w7, acc2[j]))));
        }
    }

    // ---- packed intra-wave reduction: 14 + 35 cross-lane ops ----
    #pragma unroll
    for (int j = 0; j < Hk; ++j) {
        acc1[j] += __shfl_xor(acc1[j], 32);
        acc2[j] += __shfl_xor(acc2[j], 32);
    }
    float val[Hk];
    #pragma unroll
    for (int j = 0; j < Hk; ++j)
        val[j] = (lane < 32) ? acc1[j] : acc2[j];
    #pragma unroll
    for (int off = 16; off >= 1; off >>= 1) {
        #pragma unroll
        for (int j = 0; j < Hk; ++j)
            val[j] += __shfl_xor(val[j], off);
    }
    // lane 0: expert-1 quarter-partials; lane 32: expert-2.

    if ((lane & 31) == 0) {
        const int e = lane >> 5;
        #pragma unroll
        for (int j = 0; j < Hk; ++j)
            red[e][j][q] = val[j];
    }
    __syncthreads();

    // ---- alpha: every lane redundantly (LDS broadcast reads) ----
    float l1 = 0.f, l2 = 0.f;
    #pragma unroll
    for (int j = 0; j < Hk; ++j) {
        const float4 r1q = *reinterpret_cast<const float4*>(&red[0][j][0]);
        const float4 r2q = *reinterpret_cast<const float4*>(&red[1][j][0]);
        const float h1 = r1q.x + r1q.y + r1q.z + r1q.w + b1r[j];
        const float h2 = r2q.x + r2q.y + r2q.z + r2q.w + b1r[j];
        l1 = fmaf(fmaxf(h1, 0.f), sr[j], l1);
        l2 = fmaf(fmaxf(h2, 0.f), sr[j], l2);
    }
    const float delta = (l2 - l1) * (1.f / 7.f);  // sum(b2) cancels
    const float a0 = 1.f / (1.f + expf(delta));   // weight of expert 1
    const float a1 = 1.f - a0;

    // ---- combine FROM REGISTERS (zero re-read) ----
    float4* __restrict__ ov = reinterpret_cast<float4*>(out + base);
    #pragma unroll
    for (int i = 0; i < 4; ++i) {
        float4 o;
        o.x = fmaf(a0, a[i].x, a1 * b[i].x);
        o.y = fmaf(a0, a[i].y, a1 * b[i].y);
        o.z = fmaf(a0, a[i].z, a1 * b[i].z);
        o.w = fmaf(a0, a[i].w, a1 * b[i].w);
        ov[vq0 + i * 64] = o;
    }
}

// Fallback (ws too small): direct-W1 f32 path (known correct, from R1).
__global__ __launch_bounds__(256, 4)
void gating_fused_direct(const float* __restrict__ f1,
                         const float* __restrict__ f2,
                         const float* __restrict__ W1,
                         const float* __restrict__ b1,
                         const float* __restrict__ W2,
                         const float* __restrict__ b2,
                         float* __restrict__ out)
{
    constexpr int VPT = 4;
    const int row = blockIdx.x;
    const int t   = threadIdx.x;
    const long long base = (long long)row * Dk;

    const float4* f1v = reinterpret_cast<const float4*>(f1 + base);
    const float4* f2v = reinterpret_cast<const float4*>(f2 + base);

    float4 r1[VPT], r2[VPT];
    float acc1[Hk], acc2[Hk];
    #pragma unroll
    for (int j = 0; j < Hk; ++j) { acc1[j] = 0.f; acc2[j] = 0.f; }

    #pragma unroll
    for (int k = 0; k < VPT; ++k) {
        const int vi = k * 256 + t;
        r1[k] = f1v[vi];
        r2[k] = f2v[vi];
        const float4* wv = reinterpret_cast<const float4*>(W1 + (long long)vi * 28);
        float4 w4[7];
        #pragma unroll
        for (int qq = 0; qq < 7; ++qq) w4[qq] = wv[qq];
        const float* ws = reinterpret_cast<const float*>(w4);
        const float* x1 = reinterpret_cast<const float*>(&r1[k]);
        const float* x2 = reinterpret_cast<const float*>(&r2[k]);
        #pragma unroll
        for (int r = 0; r < 4; ++r)
            #pragma unroll
            for (int j = 0; j < Hk; ++j) {
                acc1[j] = fmaf(x1[r], ws[r * 7 + j], acc1[j]);
                acc2[j] = fmaf(x2[r], ws[r * 7 + j], acc2[j]);
            }
    }
    #pragma unroll
    for (int j = 0; j < Hk; ++j)
        #pragma unroll
        for (int off = 32; off >= 1; off >>= 1) {
            acc1[j] += __shfl_down(acc1[j], off);
            acc2[j] += __shfl_down(acc2[j], off);
        }

    __shared__ float red[4][2 * Hk];
    __shared__ float alpha[2];
    const int wave = t >> 6;
    const int lane = t & 63;
    if (lane == 0)
        #pragma unroll
        for (int j = 0; j < Hk; ++j) {
            red[wave][j]      = acc1[j];
            red[wave][Hk + j] = acc2[j];
        }
    __syncthreads();

    if (t == 0) {
        float l1 = 0.f, l2 = 0.f;
        #pragma unroll
        for (int j = 0; j < Hk; ++j) {
            float h1 = red[0][j] + red[1][j] + red[2][j] + red[3][j] + b1[j];
            float h2 = red[0][Hk + j] + red[1][Hk + j] + red[2][Hk + j]
                     + red[3][Hk + j] + b1[j];
            float s = 0.f;
            #pragma unroll
            for (int k2 = 0; k2 < Hk; ++k2) s += W2[j * Hk + k2];
            l1 = fmaf(fmaxf(h1, 0.f), s, l1);
            l2 = fmaf(fmaxf(h2, 0.f), s, l2);
        }
        float sb2 = 0.f;
        #pragma unroll
        for (int k2 = 0; k2 < Hk; ++k2) sb2 += b2[k2];
        l1 = (l1 + sb2) * (1.f / 7.f);
        l2 = (l2 + sb2) * (1.f / 7.f);
        const float a0 = 1.f / (1.f + expf(l2 - l1));
        alpha[0] = a0;
        alpha[1] = 1.f - a0;
    }
    __syncthreads();

    const float a0 = alpha[0];
    const float a1 = alpha[1];
    float4* ov = reinterpret_cast<float4*>(out + base);
    #pragma unroll
    for (int k = 0; k < VPT; ++k) {
        const int vi = k * 256 + t;
        float4 o;
        o.x = a0 * r1[k].x + a1 * r2[k].x;
        o.y = a0 * r1[k].y + a1 * r2[k].y;
        o.z = a0 * r1[k].z + a1 * r2[k].z;
        o.w = a0 * r1[k].w + a1 * r2[k].w;
        ov[vi] = o;
    }
}

extern "C" void kernel_launch(void* const* d_in, const int* in_sizes, int n_in,
                              void* d_out, int out_size, void* d_ws, size_t ws_size,
                              hipStream_t stream) {
    const float* f1 = (const float*)d_in[0];
    const float* f2 = (const float*)d_in[1];
    const float* W1 = (const float*)d_in[2];
    const float* b1 = (const float*)d_in[3];
    const float* W2 = (const float*)d_in[4];
    const float* b2 = (const float*)d_in[5];
    float* out = (float*)d_out;
    const int rows = in_sizes[0] / Dk;   // 16384

    if (ws_size >= WS_NEEDED) {
        unsigned int* wsw = (unsigned int*)d_ws;
        gating_prep<<<(NWE + 255) / 256, 256, 0, stream>>>(W1, b1, W2, b2, wsw);
        gating_wave<<<rows, NTH, 0, stream>>>(
            f1, f2, reinterpret_cast<const uint4*>(wsw),
            reinterpret_cast<const float*>(wsw) + WPK_WORDS, out, rows);
    } else {
        gating_fused_direct<<<rows, 256, 0, stream>>>(f1, f2, W1, b1, W2, b2, out);
    }
}

// Round 19
// 146.326 us; speedup vs baseline: 2.3326x; 2.3326x over previous
//
#include <hip/hip_runtime.h>
#include <hip/hip_bf16.h>

// GatingNetwork: B=16384 rows, D=4096, H=OUT=7.
// R19 = R16 restored verbatim (best measured: 147us).
// R18's launch_bounds(256,8) forced a 64-VGPR cap == R16's measured usage;
// the allocator needs headroom and spilled (WRITE 262->977MB, 341us).
// R16's proven configuration: 512 thr = 8 waves = 2 rows x 4 quarters,
// grid 8192 sequential blocks, weights streamed directly from the L2-hot
// packed bf16 buffer into the FMA (no LDS roundtrip, no staging barrier),
// 8-load HBM burst per wave, 49-op packed reduce, 448B LDS exchange,
// lane-uniform alpha, combine from registers. launch_bounds(512,2) leaves
// the allocator slack: measured 64 VGPR, zero spill, FETCH=WRITE=262MB.

constexpr int Dk  = 4096;
constexpr int Hk  = 7;
constexpr int NPAIR = Dk / 512;                  // 8 pair-iters (512 floats)
constexpr int NWE   = Hk * NPAIR * 64;           // 3584 uint4 weight entries
constexpr int WPK_WORDS = NWE * 4;               // 14336 u32 words (57344 B)
constexpr size_t WS_NEEDED = (size_t)WPK_WORDS * 4 + 64;

constexpr int NTH = 512;                         // 8 waves per block
constexpr int RPB = 2;                           // rows per block (4 waves/row)

// gc floats at word offset WPK_WORDS: b1[7], s_j[7], sum(b2) at [14].
__global__ void gating_prep(const float* __restrict__ W1,
                            const float* __restrict__ b1,
                            const float* __restrict__ W2,
                            const float* __restrict__ b2,
                            unsigned int* __restrict__ wsw)
{
    const int t = blockIdx.x * blockDim.x + threadIdx.x;   // one thread/uint4
    if (t < NWE) {
        const int j    = t / (NPAIR * 64);
        const int kk   = (t / 64) % NPAIR;
        const int lane = t & 63;
        const int vi0  = (2 * kk) * 64 + lane;             // float4 idx, iter A
        unsigned int w[4];
        #pragma unroll
        for (int h = 0; h < 2; ++h) {                      // iter A / iter B
            const int vi = vi0 + h * 64;
            #pragma unroll
            for (int p = 0; p < 2; ++p) {                  // element pair
                const int d0 = 4 * vi + 2 * p;
                const unsigned int lo = (unsigned int)__bfloat16_as_ushort(
                    __float2bfloat16(W1[(long long)d0 * Hk + j]));
                const unsigned int hi = (unsigned int)__bfloat16_as_ushort(
                    __float2bfloat16(W1[(long long)(d0 + 1) * Hk + j]));
                w[h * 2 + p] = lo | (hi << 16);
            }
        }
        reinterpret_cast<uint4*>(wsw)[t] = make_uint4(w[0], w[1], w[2], w[3]);
    }
    if (blockIdx.x == 0 && threadIdx.x == 0) {
        float* c = reinterpret_cast<float*>(wsw) + WPK_WORDS;
        #pragma unroll
        for (int j = 0; j < Hk; ++j) {
            c[j] = b1[j];
            float s = 0.f;
            #pragma unroll
            for (int k = 0; k < Hk; ++k) s += W2[j * Hk + k];
            c[Hk + j] = s;
        }
        float sb2 = 0.f;
        #pragma unroll
        for (int k = 0; k < Hk; ++k) sb2 += b2[k];
        c[14] = sb2;
    }
}

__device__ __forceinline__ float bf_lo(unsigned int u) {
    return __uint_as_float(u << 16);
}
__device__ __forceinline__ float bf_hi(unsigned int u) {
    return __uint_as_float(u & 0xFFFF0000u);
}

__global__ __launch_bounds__(NTH, 2)
void gating_wave(const float* __restrict__ f1,
                 const float* __restrict__ f2,
                 const uint4* __restrict__ wpk,   // [7][8][64] packed weights
                 const float* __restrict__ gc,    // b1[7], s[7], sb2
                 float* __restrict__ out,
                 int rows)
{
    __shared__ float red[RPB][2][Hk][4];         // 448 B

    const int wid  = threadIdx.x >> 6;
    const int lane = threadIdx.x & 63;
    const int lrow = wid >> 2;                   // row within block (0..1)
    const int q    = wid & 3;                    // quarter of the row
    const int vq0  = 4 * q * 64 + lane;          // float4 idx within row

    // ---- One-time: this wave's weight fragment -> 14 uint4 registers ----
    uint4 wr0[Hk], wr1[Hk];                      // kk = 2q, 2q+1
    #pragma unroll
    for (int j = 0; j < Hk; ++j) {
        wr0[j] = wpk[(j * NPAIR + 2 * q)     * 64 + lane];
        wr1[j] = wpk[(j * NPAIR + 2 * q + 1) * 64 + lane];
    }
    // Hoist gate constants.
    float b1r[Hk], sr[Hk];
    #pragma unroll
    for (int j = 0; j < Hk; ++j) { b1r[j] = gc[j]; sr[j] = gc[Hk + j]; }

    int row = blockIdx.x * RPB + lrow;
    if (row >= rows) row = rows - 1;             // clamp (barrier: no return)
    const long long base = (long long)row * Dk;
    const float4* __restrict__ f1v = reinterpret_cast<const float4*>(f1 + base);
    const float4* __restrict__ f2v = reinterpret_cast<const float4*>(f2 + base);

    // ---- Burst this quarter's 8 loads (8 KB in flight) ----
    float4 a[4], b[4];
    #pragma unroll
    for (int i = 0; i < 4; ++i) {
        a[i] = f1v[vq0 + i * 64];
        b[i] = f2v[vq0 + i * 64];
    }
    __builtin_amdgcn_sched_barrier(0);           // keep the 8 loads batched

    float acc1[Hk], acc2[Hk];
    #pragma unroll
    for (int j = 0; j < Hk; ++j) { acc1[j] = 0.f; acc2[j] = 0.f; }

    // ---- Gate FMAs: pure VALU, weights from registers ----
    #pragma unroll
    for (int kk2 = 0; kk2 < 2; ++kk2) {
        const float4 xa0 = a[2 * kk2],     xb0 = b[2 * kk2];
        const float4 xa1 = a[2 * kk2 + 1], xb1 = b[2 * kk2 + 1];
        #pragma unroll
        for (int j = 0; j < Hk; ++j) {
            const uint4 u = kk2 ? wr1[j] : wr0[j];
            const float w0 = bf_lo(u.x), w1 = bf_hi(u.x);
            const float w2 = bf_lo(u.y), w3 = bf_hi(u.y);
            const float w4 = bf_lo(u.z), w5 = bf_hi(u.z);
            const float w6 = bf_lo(u.w), w7 = bf_hi(u.w);
            acc1[j] = fmaf(xa0.x, w0, fmaf(xa0.y, w1,
                      fmaf(xa0.z, w2, fmaf(xa0.w, w3, acc1[j]))));
            acc1[j] = fmaf(xa1.x, w4, fmaf(xa1.y, w5,
                      fmaf(xa1.z, w6, fmaf(xa1.w, w7, acc1[j]))));
            acc2[j] = fmaf(xb0.x, w0, fmaf(xb0.y, w1,
                      fmaf(xb0.z, w2, fmaf(xb0.w, w3, acc2[j]))));
            acc2[j] = fmaf(xb1.x, w4, fmaf(xb1.y, w5,
                      fmaf(xb1.z, w6, fmaf(xb1.w, w7, acc2[j]))));
        }
    }

    // ---- packed intra-wave reduction: 14 + 35 cross-lane ops ----
    #pragma unroll
    for (int j = 0; j < Hk; ++j) {
        acc1[j] += __shfl_xor(acc1[j], 32);
        acc2[j] += __shfl_xor(acc2[j], 32);
    }
    float val[Hk];
    #pragma unroll
    for (int j = 0; j < Hk; ++j)
        val[j] = (lane < 32) ? acc1[j] : acc2[j];
    #pragma unroll
    for (int off = 16; off >= 1; off >>= 1) {
        #pragma unroll
        for (int j = 0; j < Hk; ++j)
            val[j] += __shfl_xor(val[j], off);
    }
    // lane 0: expert-1 quarter-partials; lane 32: expert-2.

    if ((lane & 31) == 0) {
        const int e = lane >> 5;
        #pragma unroll
        for (int j = 0; j < Hk; ++j)
            red[lrow][e][j][q] = val[j];
    }
    __syncthreads();

    // ---- alpha: every lane redundantly (LDS broadcast reads) ----
    float l1 = 0.f, l2 = 0.f;
    #pragma unroll
    for (int j = 0; j < Hk; ++j) {
        const float4 r1q = *reinterpret_cast<const float4*>(&red[lrow][0][j][0]);
        const float4 r2q = *reinterpret_cast<const float4*>(&red[lrow][1][j][0]);
        const float h1 = r1q.x + r1q.y + r1q.z + r1q.w + b1r[j];
        const float h2 = r2q.x + r2q.y + r2q.z + r2q.w + b1r[j];
        l1 = fmaf(fmaxf(h1, 0.f), sr[j], l1);
        l2 = fmaf(fmaxf(h2, 0.f), sr[j], l2);
    }
    const float delta = (l2 - l1) * (1.f / 7.f);  // sum(b2) cancels
    const float a0 = 1.f / (1.f + expf(delta));   // weight of expert 1
    const float a1 = 1.f - a0;

    // ---- combine FROM REGISTERS (zero re-read) ----
    float4* __restrict__ ov = reinterpret_cast<float4*>(out + base);
    #pragma unroll
    for (int i = 0; i < 4; ++i) {
        float4 o;
        o.x = fmaf(a0, a[i].x, a1 * b[i].x);
        o.y = fmaf(a0, a[i].y, a1 * b[i].y);
        o.z = fmaf(a0, a[i].z, a1 * b[i].z);
        o.w = fmaf(a0, a[i].w, a1 * b[i].w);
        ov[vq0 + i * 64] = o;
    }
}

// Fallback (ws too small): direct-W1 f32 path (known correct, from R1).
__global__ __launch_bounds__(256, 4)
void gating_fused_direct(const float* __restrict__ f1,
                         const float* __restrict__ f2,
                         const float* __restrict__ W1,
                         const float* __restrict__ b1,
                         const float* __restrict__ W2,
                         const float* __restrict__ b2,
                         float* __restrict__ out)
{
    constexpr int VPT = 4;
    const int row = blockIdx.x;
    const int t   = threadIdx.x;
    const long long base = (long long)row * Dk;

    const float4* f1v = reinterpret_cast<const float4*>(f1 + base);
    const float4* f2v = reinterpret_cast<const float4*>(f2 + base);

    float4 r1[VPT], r2[VPT];
    float acc1[Hk], acc2[Hk];
    #pragma unroll
    for (int j = 0; j < Hk; ++j) { acc1[j] = 0.f; acc2[j] = 0.f; }

    #pragma unroll
    for (int k = 0; k < VPT; ++k) {
        const int vi = k * 256 + t;
        r1[k] = f1v[vi];
        r2[k] = f2v[vi];
        const float4* wv = reinterpret_cast<const float4*>(W1 + (long long)vi * 28);
        float4 w4[7];
        #pragma unroll
        for (int qq = 0; qq < 7; ++qq) w4[qq] = wv[qq];
        const float* ws = reinterpret_cast<const float*>(w4);
        const float* x1 = reinterpret_cast<const float*>(&r1[k]);
        const float* x2 = reinterpret_cast<const float*>(&r2[k]);
        #pragma unroll
        for (int r = 0; r < 4; ++r)
            #pragma unroll
            for (int j = 0; j < Hk; ++j) {
                acc1[j] = fmaf(x1[r], ws[r * 7 + j], acc1[j]);
                acc2[j] = fmaf(x2[r], ws[r * 7 + j], acc2[j]);
            }
    }
    #pragma unroll
    for (int j = 0; j < Hk; ++j)
        #pragma unroll
        for (int off = 32; off >= 1; off >>= 1) {
            acc1[j] += __shfl_down(acc1[j], off);
            acc2[j] += __shfl_down(acc2[j], off);
        }

    __shared__ float red[4][2 * Hk];
    __shared__ float alpha[2];
    const int wave = t >> 6;
    const int lane = t & 63;
    if (lane == 0)
        #pragma unroll
        for (int j = 0; j < Hk; ++j) {
            red[wave][j]      = acc1[j];
            red[wave][Hk + j] = acc2[j];
        }
    __syncthreads();

    if (t == 0) {
        float l1 = 0.f, l2 = 0.f;
        #pragma unroll
        for (int j = 0; j < Hk; ++j) {
            float h1 = red[0][j] + red[1][j] + red[2][j] + red[3][j] + b1[j];
            float h2 = red[0][Hk + j] + red[1][Hk + j] + red[2][Hk + j]
                     + red[3][Hk + j] + b1[j];
            float s = 0.f;
            #pragma unroll
            for (int k2 = 0; k2 < Hk; ++k2) s += W2[j * Hk + k2];
            l1 = fmaf(fmaxf(h1, 0.f), s, l1);
            l2 = fmaf(fmaxf(h2, 0.f), s, l2);
        }
        float sb2 = 0.f;
        #pragma unroll
        for (int k2 = 0; k2 < Hk; ++k2) sb2 += b2[k2];
        l1 = (l1 + sb2) * (1.f / 7.f);
        l2 = (l2 + sb2) * (1.f / 7.f);
        const float a0 = 1.f / (1.f + expf(l2 - l1));
        alpha[0] = a0;
        alpha[1] = 1.f - a0;
    }
    __syncthreads();

    const float a0 = alpha[0];
    const float a1 = alpha[1];
    float4* ov = reinterpret_cast<float4*>(out + base);
    #pragma unroll
    for (int k = 0; k < VPT; ++k) {
        const int vi = k * 256 + t;
        float4 o;
        o.x = a0 * r1[k].x + a1 * r2[k].x;
        o.y = a0 * r1[k].y + a1 * r2[k].y;
        o.z = a0 * r1[k].z + a1 * r2[k].z;
        o.w = a0 * r1[k].w + a1 * r2[k].w;
        ov[vi] = o;
    }
}

extern "C" void kernel_launch(void* const* d_in, const int* in_sizes, int n_in,
                              void* d_out, int out_size, void* d_ws, size_t ws_size,
                              hipStream_t stream) {
    const float* f1 = (const float*)d_in[0];
    const float* f2 = (const float*)d_in[1];
    const float* W1 = (const float*)d_in[2];
    const float* b1 = (const float*)d_in[3];
    const float* W2 = (const float*)d_in[4];
    const float* b2 = (const float*)d_in[5];
    float* out = (float*)d_out;
    const int rows = in_sizes[0] / Dk;   // 16384

    if (ws_size >= WS_NEEDED) {
        unsigned int* wsw = (unsigned int*)d_ws;
        gating_prep<<<(NWE + 255) / 256, 256, 0, stream>>>(W1, b1, W2, b2, wsw);
        const int blocks = (rows + RPB - 1) / RPB;   // 8192
        gating_wave<<<blocks, NTH, 0, stream>>>(
            f1, f2, reinterpret_cast<const uint4*>(wsw),
            reinterpret_cast<const float*>(wsw) + WPK_WORDS, out, rows);
    } else {
        gating_fused_direct<<<rows, 256, 0, stream>>>(f1, f2, W1, b1, W2, b2, out);
    }
}